// Round 1
// baseline (5599.323 us; speedup 1.0000x reference)
//
#include <hip/hip_runtime.h>
#include <stdint.h>

// Problem constants
#define B_  256
#define S_  512
#define E_  100
#define H_  512
#define G_  2048          // 4H
#define KH  512           // h part of K
#define KX  128           // padded x part of K
#define K_  640           // KH + KX
#define KT  20            // K_/32 MFMA K-tiles
#define ALD 648           // padded LDS row (halfs): 648*2=1296B -> 324 words -> bank stride 4

typedef _Float16 half8 __attribute__((ext_vector_type(8)));
typedef float   f32x4 __attribute__((ext_vector_type(4)));

// ws layout (bytes)
#define OFF_WC   0u          // [G][K_] f16      : 2,621,440
#define OFF_HBUF 2621440u    // [2][B][H] f16    :   524,288
#define OFF_XBUF 3145728u    // [S][B][KX] f16   : 33,554,432
#define OFF_BIAS 36700160u   // [G] f32          :     8,192
#define OFF_FLAG 36708352u   // [16][16] u32     :     1,024
#define WS_NEED  36709376u

// ---------------------------------------------------------------- prep: W + bias
__global__ void prep_wc(const float* __restrict__ Wih, const float* __restrict__ Whh,
                        const float* __restrict__ bih, const float* __restrict__ bhh,
                        _Float16* __restrict__ Wc, float* __restrict__ bias) {
    int idx = blockIdx.x * 256 + threadIdx.x;     // < G_*K_
    int g = idx / K_;
    int k = idx - g * K_;
    float v = 0.f;
    if (k < KH)            v = Whh[g * KH + k];
    else if (k < KH + E_)  v = Wih[g * E_ + (k - KH)];
    Wc[idx] = (_Float16)v;
    if (k == 0) bias[g] = bih[g] + bhh[g];
}

// ---------------------------------------------------------------- prep: embed gather
__global__ void prep_x(const int* __restrict__ sent, const float* __restrict__ emb,
                       _Float16* __restrict__ xbuf) {
    size_t idx = (size_t)blockIdx.x * 256 + threadIdx.x;  // < S_*B_*KX = 2^24
    int k = (int)(idx & (KX - 1));
    int b = (int)((idx >> 7) & (B_ - 1));
    int t = (int)(idx >> 15);
    int tok = sent[b * S_ + t];
    float v = (k < E_) ? emb[(size_t)tok * E_ + k] : 0.f;
    xbuf[idx] = (_Float16)v;
}

// ---------------------------------------------------------------- persistent LSTM
__global__ __launch_bounds__(256, 1) void lstm_persist(
    const _Float16* __restrict__ Wc, _Float16* __restrict__ hbuf,
    const _Float16* __restrict__ xbuf, const float* __restrict__ bias,
    unsigned int* __restrict__ flags, float* __restrict__ out)
{
    const int tid = threadIdx.x;
    const int L   = tid & 63;
    const int w   = tid >> 6;          // wave = gate type (0:i 1:f 2:g 3:o)
    // XCD-aware swizzle: batch-row r's 16 col-blocks share one XCD (perf heuristic)
    const int bx  = blockIdx.x;
    const int xcd = bx & 7;
    const int kk_ = bx >> 3;           // 0..31
    const int r   = (xcd << 1) | (kk_ >> 4);   // batch-row 0..15
    const int c   = kk_ & 15;                  // hcol-tile 0..15
    const int brow0 = r << 4;          // 16 batches
    const int hcol0 = c << 5;          // 32 h cols

    __shared__ __align__(16) _Float16 Alds[16][ALD];   // [batch][K_], padded
    __shared__ float gbuf[4][16][33];                  // [type][batch][hcol], padded

    // ---- B-fragment preload (W resident in registers: 2 ntiles x 20 ktiles x 16B)
    half8 bfrag[2][KT];
#pragma unroll
    for (int n = 0; n < 2; ++n) {
        const _Float16* gp = Wc + (size_t)((w << 9) + hcol0 + (n << 4) + (L & 15)) * K_
                                + ((L >> 4) << 3);
#pragma unroll
        for (int kt = 0; kt < KT; ++kt)
            bfrag[n][kt] = *reinterpret_cast<const half8*>(gp + kt * 32);
    }

    // ---- per-thread update-state: thread owns h/c values v0=2*tid, v0+1
    const int v0 = tid << 1;
    const int bl = v0 >> 5;            // batch-within-tile 0..15
    const int j0 = v0 & 31;            // hcol-within-tile (even)
    const float bi0 = bias[hcol0 + j0],          bi1 = bias[hcol0 + j0 + 1];
    const float bf0 = bias[512  + hcol0 + j0],   bf1 = bias[512  + hcol0 + j0 + 1];
    const float bg0 = bias[1024 + hcol0 + j0],   bg1 = bias[1024 + hcol0 + j0 + 1];
    const float bo0 = bias[1536 + hcol0 + j0],   bo1 = bias[1536 + hcol0 + j0 + 1];
    float c0 = 0.f, c1 = 0.f;

    unsigned int* rowflags = flags + r * 16;

    for (int t = 0; t < S_; ++t) {
        // ---- 1. wait for h_t from all 16 blocks of this batch-row
        if (t > 0 && tid < 16) {
            int polls = 0;
            while (__hip_atomic_load(&rowflags[tid], __ATOMIC_RELAXED,
                                     __HIP_MEMORY_SCOPE_AGENT) < (unsigned)t) {
                if (((++polls) & 4095) == 0)
                    __builtin_amdgcn_fence(__ATOMIC_ACQUIRE, "agent");  // missed-wakeup insurance
                if (polls > 10000000) break;   // safety valve (should never trip)
            }
        }
        __syncthreads();
        __builtin_amdgcn_fence(__ATOMIC_ACQUIRE, "agent");   // invalidate stale L1/L2 h lines

        // ---- 2. stage A = [h_t | x_t] tile into LDS
        const _Float16* hsrc = hbuf + ((t & 1) ? (B_ * H_) : 0);
#pragma unroll
        for (int it = 0; it < 4; ++it) {
            int q  = it * 256 + tid;           // 1024 chunks of 8 halfs
            int bb = q >> 6;
            int ck = (q & 63) << 3;
            *reinterpret_cast<half8*>(&Alds[bb][ck]) =
                *reinterpret_cast<const half8*>(hsrc + (size_t)(brow0 + bb) * H_ + ck);
        }
        {
            int bb = tid >> 4;
            int ck = (tid & 15) << 3;
            *reinterpret_cast<half8*>(&Alds[bb][KH + ck]) =
                *reinterpret_cast<const half8*>(xbuf + ((size_t)t * B_ + brow0 + bb) * KX + ck);
        }
        __syncthreads();

        // ---- 3. MFMA: wave w computes gate-type w, 2 ntiles, K=640 (4 acc chains)
        f32x4 acc00 = {0,0,0,0}, acc01 = {0,0,0,0}, acc10 = {0,0,0,0}, acc11 = {0,0,0,0};
        const int arow = L & 15;
        const int aoff = (L >> 4) << 3;
#pragma unroll
        for (int kt = 0; kt < KT; ++kt) {
            half8 a = *reinterpret_cast<const half8*>(&Alds[arow][kt * 32 + aoff]);
            if (kt & 1) {
                acc01 = __builtin_amdgcn_mfma_f32_16x16x32_f16(a, bfrag[0][kt], acc01, 0, 0, 0);
                acc11 = __builtin_amdgcn_mfma_f32_16x16x32_f16(a, bfrag[1][kt], acc11, 0, 0, 0);
            } else {
                acc00 = __builtin_amdgcn_mfma_f32_16x16x32_f16(a, bfrag[0][kt], acc00, 0, 0, 0);
                acc10 = __builtin_amdgcn_mfma_f32_16x16x32_f16(a, bfrag[1][kt], acc10, 0, 0, 0);
            }
        }
        f32x4 g0 = acc00 + acc01;
        f32x4 g1 = acc10 + acc11;
        {
            int grb = (L >> 4) << 2;
            int gc0 = L & 15;
#pragma unroll
            for (int rr = 0; rr < 4; ++rr) {
                gbuf[w][grb + rr][gc0]      = g0[rr];
                gbuf[w][grb + rr][16 + gc0] = g1[rr];
            }
        }
        __syncthreads();

        // ---- 4. elementwise LSTM cell update (2 values/thread, c kept in regs)
        float i0 = gbuf[0][bl][j0]     + bi0, i1 = gbuf[0][bl][j0 + 1] + bi1;
        float f0 = gbuf[1][bl][j0]     + bf0, f1 = gbuf[1][bl][j0 + 1] + bf1;
        float gg0= gbuf[2][bl][j0]     + bg0, gg1= gbuf[2][bl][j0 + 1] + bg1;
        float o0 = gbuf[3][bl][j0]     + bo0, o1 = gbuf[3][bl][j0 + 1] + bo1;
        float si0 = 1.f / (1.f + __expf(-i0));
        float sf0 = 1.f / (1.f + __expf(-f0));
        float so0 = 1.f / (1.f + __expf(-o0));
        float tg0 = tanhf(gg0);
        float si1 = 1.f / (1.f + __expf(-i1));
        float sf1 = 1.f / (1.f + __expf(-f1));
        float so1 = 1.f / (1.f + __expf(-o1));
        float tg1 = tanhf(gg1);
        c0 = sf0 * c0 + si0 * tg0;
        c1 = sf1 * c1 + si1 * tg1;
        float h0 = so0 * tanhf(c0);
        float h1 = so1 * tanhf(c1);

        if (t == S_ - 1) {
            float* op = out + (size_t)(brow0 + bl) * H_ + hcol0 + j0;
            op[0] = h0; op[1] = h1;
        } else {
            // publish h_{t+1}: agent-scope (sc1) store -> visible at LLC without relying on wb
            _Float16 hh0 = (_Float16)h0, hh1 = (_Float16)h1;
            unsigned int pack = ((unsigned int)*(unsigned short*)&hh1 << 16)
                              |  (unsigned int)*(unsigned short*)&hh0;
            unsigned int* hp = reinterpret_cast<unsigned int*>(
                hbuf + (((t + 1) & 1) ? (B_ * H_) : 0)
                     + (size_t)(brow0 + bl) * H_ + hcol0 + j0);
            __hip_atomic_store(hp, pack, __ATOMIC_RELAXED, __HIP_MEMORY_SCOPE_AGENT);
            __syncthreads();   // all waves' stores drained (compiler emits vmcnt(0) before barrier)
            if (tid == 0)
                __hip_atomic_store(&rowflags[c], (unsigned)(t + 1),
                                   __ATOMIC_RELEASE, __HIP_MEMORY_SCOPE_AGENT);
        }
    }
}

// ---------------------------------------------------------------- launch
extern "C" void kernel_launch(void* const* d_in, const int* in_sizes, int n_in,
                              void* d_out, int out_size, void* d_ws, size_t ws_size,
                              hipStream_t stream) {
    (void)in_sizes; (void)n_in; (void)out_size;
    if (ws_size < WS_NEED) return;   // clean deterministic failure if ws too small

    const int*   sent = (const int*)d_in[0];
    const float* emb  = (const float*)d_in[1];
    const float* Wih  = (const float*)d_in[2];
    const float* Whh  = (const float*)d_in[3];
    const float* bih  = (const float*)d_in[4];
    const float* bhh  = (const float*)d_in[5];

    char* ws = (char*)d_ws;
    _Float16*     Wc    = (_Float16*)(ws + OFF_WC);
    _Float16*     hbuf  = (_Float16*)(ws + OFF_HBUF);
    _Float16*     xbuf  = (_Float16*)(ws + OFF_XBUF);
    float*        bias  = (float*)(ws + OFF_BIAS);
    unsigned int* flags = (unsigned int*)(ws + OFF_FLAG);

    hipMemsetAsync(flags, 0, 16 * 16 * sizeof(unsigned int), stream);
    hipMemsetAsync(hbuf, 0, B_ * H_ * sizeof(_Float16), stream);  // h_0 = 0 (parity-0 buffer)

    prep_wc<<<(G_ * K_) / 256, 256, 0, stream>>>(Wih, Whh, bih, bhh, Wc, bias);
    prep_x<<<(S_ * B_ * KX) / 256, 256, 0, stream>>>(sent, emb, xbuf);
    lstm_persist<<<256, 256, 0, stream>>>(Wc, hbuf, xbuf, bias, flags, (float*)d_out);
}